// Round 14
// baseline (1141.688 us; speedup 1.0000x reference)
//
#include <hip/hip_runtime.h>
#include <hip/hip_bf16.h>

#define NIN    512
#define NEVAL  1536
#define NCOLS  2048
#define NOUT   256
#define OUT_BASE 1280
#define NBLK   48       // NEVAL / 32

typedef __attribute__((ext_vector_type(8))) short short8;   // 8 bf16 (4 VGPRs)
typedef __attribute__((ext_vector_type(4))) float floatx4;  // MFMA C/D

// ---------- helpers ----------

__device__ __forceinline__ unsigned short f2bf(float f) {
    __hip_bfloat16 h = __float2bfloat16(f);
    return __builtin_bit_cast(unsigned short, h);
}
__device__ __forceinline__ unsigned pack2(float a, float b) {
    return (unsigned)f2bf(a) | ((unsigned)f2bf(b) << 16);
}
// sigmoid(clip(5z,-60,60)): clamp dropped — v_exp overflow gives exact 0/1.
__device__ __forceinline__ float sigmoid5(float z) {
    return __builtin_amdgcn_rcpf(1.0f + __expf(-5.0f * z));
}

// ---------- W fp32 -> bf16 (d_ws re-poisoned every launch, so rerun) ----------

__global__ __launch_bounds__(256) void wconv(const float* __restrict__ W,
                                             ushort* __restrict__ Wb, int n8) {
    int i = blockIdx.x * blockDim.x + threadIdx.x;
    if (i < n8) {
        float4 v0 = ((const float4*)W)[2 * i];
        float4 v1 = ((const float4*)W)[2 * i + 1];
        uint4 pk;
        pk.x = pack2(v0.x, v0.y); pk.y = pack2(v0.z, v0.w);
        pk.z = pack2(v1.x, v1.y); pk.w = pack2(v1.z, v1.w);
        ((uint4*)Wb)[i] = pk;
    }
}

// ---------- main kernel ----------
// 256 WGs x 1024 threads (16 waves), 1 WG/CU. WG owns 16 rows.
// ROUND-14 = ROUND-13 structure (single-wave chain: wave 0, lane r = row r,
// per-lane z for all 32 nodes; sigmoid on own register — no cross-lane on
// the serial path; rank-1 updates from uniform-address ds_read_b128) with
// the R13 spill fixed:
//   * __launch_bounds__(1024, 4): true occupancy is 4 waves/SIMD (LDS caps
//     at 1 WG/CU), raising the VGPR budget 64->128. R13's compiler targeted
//     8 waves/SIMD, allocated 64 VGPRs, and spilled z[32] to scratch ->
//     528 MB/dispatch of HBM scratch traffic (the 1073us).
//   * z held in 8 NAMED float4s (Z0..Z7), steps fully macro-unrolled with
//     constant component selects — no array for the allocator to demote.
// Per 32-node block k (cols [L0, L0+32), L0 = 512+32k):
//   A: barrier — chain(k-1) O/Wt/Zfin-reads done
//   all: Wt stage (Wt[col*36+node]), main(k+1) MFMAs, tail MFMA
//        (owner ksp==(k+7)&7), Zred write
//   B: barrier — Zred visible
//   all: gather 8 partials + bias -> Zfin[node*17+row]
//   C: barrier — Zfin visible
//   wave0: chain (32 steps); writes o -> O (bf16) + out (global)

__global__ __launch_bounds__(1024, 4) void ffnet(const float* __restrict__ x,
                                                 const float* __restrict__ W,
                                                 const ushort* __restrict__ Wb,
                                                 const float* __restrict__ bias,
                                                 float* __restrict__ out) {
    __shared__ unsigned short O[16 * 2048];   // 64 KB
    __shared__ float Zred[16 * 256];          // 16 KB [wave][lane][reg]
    __shared__ float Wt[32 * 36];             // 4.6 KB diag, Wt[col*36+node]
    __shared__ float Zfin[32 * 17];           // 2.2 KB z-init, [node*17+row]

    const int t    = threadIdx.x;
    const int w    = t >> 6;        // wave 0..15
    const int lane = t & 63;

    // phase-A role: 2 node-halves x 8 K-split slots
    const int m16  = lane & 15;     // A row (batch row) / D col (node)
    const int quad = lane >> 4;     // 0..3
    const int half = w >> 3;        // 0..1
    const int ksp  = w & 7;         // 0..7
    const int arow = m16 << 11;
    const int arot = m16 << 3;

    const int ii   = lane & 31;     // node within block (gather role)
    const long row = (long)blockIdx.x * 16 + w;
    const int rot  = w << 3;

    // chain role (wave 0): lane r16 = batch row (lanes 16-63 mirror)
    const int r16  = lane & 15;
    const long ob  = ((long)blockIdx.x * 16 + r16) * NOUT - OUT_BASE;

    // Wt staging role: one float per thread
    const int sn = t >> 5;          // 0..31 node i
    const int sc = t & 31;          // 0..31 col j

    // ---- stage x row w into LDS as bf16 (swizzled) ----
    {
        const float* xr = x + row * NIN + lane * 8;
        float4 v0 = *(const float4*)xr;
        float4 v1 = *(const float4*)(xr + 4);
        uint4 pk;
        pk.x = pack2(v0.x, v0.y); pk.y = pack2(v0.z, v0.w);
        pk.z = pack2(v1.x, v1.y); pk.w = pack2(v1.z, v1.w);
        *(uint4*)&O[(w << 11) + ((lane * 8 + rot) & 2047)] = pk;
    }
    __syncthreads();

    // ---- prologue: main(0) over columns [0, 480) ----
    floatx4 acc = {0.f, 0.f, 0.f, 0.f};
    {
        const ushort* wb = Wb + (size_t)(half * 16 + m16) * NCOLS;
        for (int kk = ksp * 32; kk < NIN - 32; kk += 256) {
            short8 a = *(const short8*)&O[arow + ((kk + quad * 8 + arot) & 2047)];
            short8 b = *(const short8*)&wb[kk + quad * 8];
            acc = __builtin_amdgcn_mfma_f32_16x16x32_bf16(a, b, acc, 0, 0, 0);
        }
    }

    for (int k = 0; k < NBLK; ++k) {
        const int i0 = k << 5;
        const int L0 = NIN + i0;
        const int g  = i0 + ii;

        __syncthreads();            // barrier A

        // Wt diag load (1 float/thread) + bias, issued early
        float wtv = W[(size_t)(i0 + sn) * NCOLS + L0 + sc];
        float bi  = bias[g];

        // main(k+1) over [0, L0) — drains overlap Wt stage / barrier B
        floatx4 accN = {0.f, 0.f, 0.f, 0.f};
        if (k + 1 < NBLK) {
            const ushort* wb = Wb + (size_t)(i0 + 32 + half * 16 + m16) * NCOLS;
            #pragma unroll 2
            for (int kk = ksp * 32; kk < L0; kk += 256) {
                short8 a = *(const short8*)&O[arow + ((kk + quad * 8 + arot) & 2047)];
                short8 b = *(const short8*)&wb[kk + quad * 8];
                accN = __builtin_amdgcn_mfma_f32_16x16x32_bf16(a, b, accN, 0, 0, 0);
            }
        }

        // stage diag weights: Wt[col*36 + node]
        Wt[sc * 36 + sn] = wtv;

        // tail: K=32 MFMA over [L0-32, L0) — chunk 15+k, owner ksp=(k+7)&7
        if (ksp == ((k + 7) & 7)) {
            const ushort* wb = Wb + (size_t)(i0 + half * 16 + m16) * NCOLS;
            const int ts = L0 - 32;
            short8 a = *(const short8*)&O[arow + ((ts + quad * 8 + arot) & 2047)];
            short8 b = *(const short8*)&wb[ts + quad * 8];
            acc = __builtin_amdgcn_mfma_f32_16x16x32_bf16(a, b, acc, 0, 0, 0);
        }

        // D frag: lane q*16+n holds Z[m=4q+reg][n]
        *(floatx4*)&Zred[(w << 8) + (lane << 2)] = acc;
        __syncthreads();            // barrier B

        // gather z-init for (row w, node ii) -> Zfin[ii*17 + w]
        {
            const int h = ii >> 4, n = ii & 15;
            const int ridx = ((w >> 2) << 6) + (n << 2) + (w & 3);
            float zacc = bi;
            #pragma unroll
            for (int p = 0; p < 8; ++p)
                zacc += Zred[(((h << 3) + p) << 8) + ridx];
            if (lane < 32)
                Zfin[ii * 17 + w] = zacc;
        }
        __syncthreads();            // barrier C: Zfin visible

        // ---- chain: wave 0 only, z in 8 named float4 registers ----
        if (w == 0) {
            float4 Z0, Z1, Z2, Z3, Z4, Z5, Z6, Z7;
            #define LDZ(G)                                                     \
                Z##G.x = Zfin[((G) * 4 + 0) * 17 + r16];                       \
                Z##G.y = Zfin[((G) * 4 + 1) * 17 + r16];                       \
                Z##G.z = Zfin[((G) * 4 + 2) * 17 + r16];                       \
                Z##G.w = Zfin[((G) * 4 + 3) * 17 + r16];
            LDZ(0) LDZ(1) LDZ(2) LDZ(3) LDZ(4) LDZ(5) LDZ(6) LDZ(7)
            #undef LDZ

            #define UP(G, J)                                                   \
                {                                                              \
                    float4 wq = *(const float4*)&Wt[(J) * 36 + (G) * 4];       \
                    Z##G.x = fmaf(wq.x, o, Z##G.x);                            \
                    Z##G.y = fmaf(wq.y, o, Z##G.y);                            \
                    Z##G.z = fmaf(wq.z, o, Z##G.z);                            \
                    Z##G.w = fmaf(wq.w, o, Z##G.w);                            \
                }
            #define SG(J, ZC)                                                  \
                float o = sigmoid5(ZC);                                        \
                if (lane < 16) {                                               \
                    O[(r16 << 11) + ((L0 + (J) + (r16 << 3)) & 2047)] =        \
                        f2bf(o);                                               \
                    if (i0 + (J) >= OUT_BASE) out[ob + i0 + (J)] = o;          \
                }
            // update groups start at (J+1)>>2 (Wt is strictly lower-tri)
            { SG( 0, Z0.x) UP(0, 0) UP(1, 0) UP(2, 0) UP(3, 0) UP(4, 0) UP(5, 0) UP(6, 0) UP(7, 0) }
            { SG( 1, Z0.y) UP(0, 1) UP(1, 1) UP(2, 1) UP(3, 1) UP(4, 1) UP(5, 1) UP(6, 1) UP(7, 1) }
            { SG( 2, Z0.z) UP(0, 2) UP(1, 2) UP(2, 2) UP(3, 2) UP(4, 2) UP(5, 2) UP(6, 2) UP(7, 2) }
            { SG( 3, Z0.w) UP(1, 3) UP(2, 3) UP(3, 3) UP(4, 3) UP(5, 3) UP(6, 3) UP(7, 3) }
            { SG( 4, Z1.x) UP(1, 4) UP(2, 4) UP(3, 4) UP(4, 4) UP(5, 4) UP(6, 4) UP(7, 4) }
            { SG( 5, Z1.y) UP(1, 5) UP(2, 5) UP(3, 5) UP(4, 5) UP(5, 5) UP(6, 5) UP(7, 5) }
            { SG( 6, Z1.z) UP(1, 6) UP(2, 6) UP(3, 6) UP(4, 6) UP(5, 6) UP(6, 6) UP(7, 6) }
            { SG( 7, Z1.w) UP(2, 7) UP(3, 7) UP(4, 7) UP(5, 7) UP(6, 7) UP(7, 7) }
            { SG( 8, Z2.x) UP(2, 8) UP(3, 8) UP(4, 8) UP(5, 8) UP(6, 8) UP(7, 8) }
            { SG( 9, Z2.y) UP(2, 9) UP(3, 9) UP(4, 9) UP(5, 9) UP(6, 9) UP(7, 9) }
            { SG(10, Z2.z) UP(2,10) UP(3,10) UP(4,10) UP(5,10) UP(6,10) UP(7,10) }
            { SG(11, Z2.w) UP(3,11) UP(4,11) UP(5,11) UP(6,11) UP(7,11) }
            { SG(12, Z3.x) UP(3,12) UP(4,12) UP(5,12) UP(6,12) UP(7,12) }
            { SG(13, Z3.y) UP(3,13) UP(4,13) UP(5,13) UP(6,13) UP(7,13) }
            { SG(14, Z3.z) UP(3,14) UP(4,14) UP(5,14) UP(6,14) UP(7,14) }
            { SG(15, Z3.w) UP(4,15) UP(5,15) UP(6,15) UP(7,15) }
            { SG(16, Z4.x) UP(4,16) UP(5,16) UP(6,16) UP(7,16) }
            { SG(17, Z4.y) UP(4,17) UP(5,17) UP(6,17) UP(7,17) }
            { SG(18, Z4.z) UP(4,18) UP(5,18) UP(6,18) UP(7,18) }
            { SG(19, Z4.w) UP(5,19) UP(6,19) UP(7,19) }
            { SG(20, Z5.x) UP(5,20) UP(6,20) UP(7,20) }
            { SG(21, Z5.y) UP(5,21) UP(6,21) UP(7,21) }
            { SG(22, Z5.z) UP(5,22) UP(6,22) UP(7,22) }
            { SG(23, Z5.w) UP(6,23) UP(7,23) }
            { SG(24, Z6.x) UP(6,24) UP(7,24) }
            { SG(25, Z6.y) UP(6,25) UP(7,25) }
            { SG(26, Z6.z) UP(6,26) UP(7,26) }
            { SG(27, Z6.w) UP(7,27) }
            { SG(28, Z7.x) UP(7,28) }
            { SG(29, Z7.y) UP(7,29) }
            { SG(30, Z7.z) UP(7,30) }
            { SG(31, Z7.w) }
            #undef SG
            #undef UP
        }
        acc = accN;
    }
}

// ---------- launch ----------

extern "C" void kernel_launch(void* const* d_in, const int* in_sizes, int n_in,
                              void* d_out, int out_size, void* d_ws, size_t ws_size,
                              hipStream_t stream) {
    const float* x  = (const float*)d_in[0];   // [4096, 512]
    const float* W  = (const float*)d_in[1];   // [1536, 2048]
    const float* b  = (const float*)d_in[2];   // [1536]
    float* out = (float*)d_out;                // [4096, 256]
    ushort* Wb = (ushort*)d_ws;                // bf16 W copy (6.3 MB)

    int n8 = NEVAL * NCOLS / 8;
    wconv<<<n8 / 256, 256, 0, stream>>>(W, Wb, n8);
    ffnet<<<4096 / 16, 1024, 0, stream>>>(x, W, Wb, b, out);
}